// Round 3
// baseline (283.776 us; speedup 1.0000x reference)
//
#include <hip/hip_runtime.h>
#include <hip/hip_bf16.h>
#include <stdint.h>

// ============================================================================
// Attention: out = softmax(mask((X_q Wq + bq)(X_k Wk + bk)^T / 8)) (X_v Wv + bv)
// B=4 S=4096 H=1024 D=64, fp32 in/out.
//
// Pipeline:
//   setup : W^T -> bf16 (plain [n][1024]), mask -> float bias {0, -1e30}
//   proj  : [R3 rewrite] one wave per 32-row strip, 1536 blocks x 64 thr.
//           A (X rows) and B (W^T rows) fragments loaded DIRECTLY from
//           global, 64-k-chunk register double-buffer prefetch, no barriers
//           in K-loop. R2 version (LDS staging, 384 blocks) was latency-
//           bound: 16% HBM, 2% VALU, 14% occupancy @ 83.6 us.
//   flash : S^T = K*Q^T per 32x32 tile, p = exp2(s*0.125*log2e + bias),
//           PV via shfl_xor(32) lane-pair exchange (C-layout -> B-operand),
//           one-pass softmax (logits bounded, no running max needed),
//           4-way key-split per block, pairwise LDS combine.
//
// q/k/vT global tiles keep the chunk-XOR swizzle (c ^ (row&7)) because flash
// stages them into LDS verbatim via global_load_lds and ds_read_b128's them.
// ============================================================================

typedef __bf16 bf16;
typedef __bf16 bf16x8 __attribute__((ext_vector_type(8)));
typedef float f32x16 __attribute__((ext_vector_type(16)));

union B8 { uint4 u; bf16x8 v; uint32_t w[4]; };

#define AS1 __attribute__((address_space(1)))
#define AS3 __attribute__((address_space(3)))

__device__ __forceinline__ void async16(const void* g, void* l) {
  __builtin_amdgcn_global_load_lds((AS1 void*)(g), (AS3 void*)(l), 16, 0, 0);
}

#define KSC 0.18033688011112042f  // 0.125 * log2(e)

// ---------------------------------------------------------------------------
// setup: items 0..24575   : W transpose+cast, one 16B wT chunk per thread
//        items 24576..28671: mask -> bias, 4 elements per thread (float4)
// wT layout: [mat][n][1024 k] bf16, plain row-major (read from global by proj)
// ---------------------------------------------------------------------------
__global__ void setup_kernel(const float* __restrict__ Wq, const float* __restrict__ Wk,
                             const float* __restrict__ Wv, const int* __restrict__ mask,
                             bf16* __restrict__ wT, float* __restrict__ biasArr)
{
  int item = blockIdx.x * 256 + threadIdx.x;
  if (item < 24576) {
    int mat = item >> 13;          // 8192 items per matrix
    int rem = item & 8191;
    int n   = rem >> 7;            // 0..63 (col of W)
    int c   = rem & 127;           // 16B chunk id along k
    const float* W = (mat == 0) ? Wq : (mat == 1) ? Wk : Wv;
    union { bf16 b[8]; uint4 u; } pk;
    #pragma unroll
    for (int j = 0; j < 8; ++j)
      pk.b[j] = (bf16)W[(c * 8 + j) * 64 + n];
    bf16* o = wT + mat * 65536;
    *(uint4*)(o + n * 1024 + c * 8) = pk.u;
  } else {
    int i = (item - 24576) << 2;
    const int4 m = *(const int4*)(mask + i);
    float4 b;
    b.x = m.x ? 0.0f : -1e30f;
    b.y = m.y ? 0.0f : -1e30f;
    b.z = m.z ? 0.0f : -1e30f;
    b.w = m.w ? 0.0f : -1e30f;
    *(float4*)(biasArr + i) = b;
  }
}

// ---------------------------------------------------------------------------
// proj: 1536 blocks x 64 threads. Block = one wave = one 32-row strip of one
// matrix. Direct-from-global fragments, 64-k-chunk register double buffer.
// ---------------------------------------------------------------------------
struct PF {            // one 64-k chunk of prefetched operands (4 K-steps)
  float4 xa[4], xb[4]; // A: 8 fp32 each step (this lane's 32B of X)
  uint4  wa[4], wb[4]; // B: 8 bf16 for n=ln and n=ln+32
};

__device__ __forceinline__ void load_chunk(const float* __restrict__ xr,
                                           const bf16* __restrict__ w0,
                                           const bf16* __restrict__ w1,
                                           int kc, PF& p) {
  #pragma unroll
  for (int s = 0; s < 4; ++s) {
    int k = kc + s * 16;
    p.xa[s] = *(const float4*)(xr + k);
    p.xb[s] = *(const float4*)(xr + k + 4);
    p.wa[s] = *(const uint4*)(w0 + k);
    p.wb[s] = *(const uint4*)(w1 + k);
  }
}

__device__ __forceinline__ void comp_chunk(const PF& p, f32x16& a0, f32x16& a1) {
  #pragma unroll
  for (int s = 0; s < 4; ++s) {
    union { bf16 b[8]; bf16x8 v; } af;
    af.b[0] = (bf16)p.xa[s].x; af.b[1] = (bf16)p.xa[s].y;
    af.b[2] = (bf16)p.xa[s].z; af.b[3] = (bf16)p.xa[s].w;
    af.b[4] = (bf16)p.xb[s].x; af.b[5] = (bf16)p.xb[s].y;
    af.b[6] = (bf16)p.xb[s].z; af.b[7] = (bf16)p.xb[s].w;
    B8 wa; wa.u = p.wa[s];
    B8 wb; wb.u = p.wb[s];
    a0 = __builtin_amdgcn_mfma_f32_32x32x16_bf16(af.v, wa.v, a0, 0, 0, 0);
    a1 = __builtin_amdgcn_mfma_f32_32x32x16_bf16(af.v, wb.v, a1, 0, 0, 0);
  }
}

__global__ __launch_bounds__(64, 2) void proj_kernel(
    const float* __restrict__ Xq, const float* __restrict__ Xk, const float* __restrict__ Xv,
    const bf16* __restrict__ wT,
    const float* __restrict__ bq, const float* __restrict__ bk, const float* __restrict__ bv,
    bf16* __restrict__ qo, bf16* __restrict__ ko, bf16* __restrict__ vTo)
{
  const int bx = blockIdx.x;
  const int mat = bx >> 9;            // 512 strips per matrix
  const int m0 = (bx & 511) << 5;     // strip base row
  const float* X    = (mat == 0) ? Xq : (mat == 1) ? Xk : Xv;
  const float* bias = (mat == 0) ? bq : (mat == 1) ? bk : bv;
  const bf16* w = wT + mat * 65536;

  __shared__ __align__(16) bf16 cs[32 * 64];   // C bounce tile (4 KB)

  const int lane = threadIdx.x;
  const int half = lane >> 5;
  const int ln = lane & 31;

  const float* xr = X + (size_t)(m0 + ln) * 1024 + half * 8;
  const bf16*  w0 = w + ln * 1024 + half * 8;
  const bf16*  w1 = w + (ln + 32) * 1024 + half * 8;

  f32x16 acc0 = {};  // n = 0..31
  f32x16 acc1 = {};  // n = 32..63

  PF A, Bp;
  load_chunk(xr, w0, w1, 0, A);
  for (int c = 0; c < 16; c += 2) {
    load_chunk(xr, w0, w1, (c + 1) * 64, Bp);
    comp_chunk(A, acc0, acc1);
    if (c + 2 < 16) load_chunk(xr, w0, w1, (c + 2) * 64, A);
    comp_chunk(Bp, acc0, acc1);
  }

  // epilogue: bias add, write un-swizzled [32 m][64 n] bf16 tile to LDS
  {
    float b0v = bias[ln];
    float b1v = bias[ln + 32];
    #pragma unroll
    for (int r = 0; r < 16; ++r) {
      int mrow = (r & 3) + 8 * (r >> 2) + 4 * half;   // C row map (m74/m101)
      cs[mrow * 64 + ln]      = (bf16)(acc0[r] + b0v);
      cs[mrow * 64 + ln + 32] = (bf16)(acc1[r] + b1v);
    }
  }
  __syncthreads();

  if (mat < 2) {
    // q/k: row-major [16384][64] bf16, chunk c of row s at slot c^(s&7)
    bf16* gout = (mat == 0) ? qo : ko;
    #pragma unroll
    for (int p = 0; p < 4; ++p) {
      int id = p * 64 + lane;
      int r = id >> 3;            // 0..31
      int c = id & 7;
      int phys = c ^ (r & 7);     // m0 % 32 == 0 so (m0+r)&7 == r&7
      *(uint4*)(gout + (size_t)(m0 + r) * 64 + phys * 8) = *(const uint4*)(cs + r * 64 + c * 8);
    }
  } else {
    // v: transposed [b][64 d][4096 s] bf16, chunk swizzle per 64-key tile
    int batch = m0 >> 12;
    int sk = m0 & 4095;           // key offset within batch
    int tb = sk & ~63;            // 64-key tile base
    int halfTile = (sk >> 5) & 1; // which half of the tile this strip covers
    #pragma unroll
    for (int p = 0; p < 4; ++p) {
      int id = p * 64 + lane;
      int d = id >> 2;            // 0..63
      int j = id & 3;             // chunk within strip
      union { bf16 b[8]; uint4 u; } pk;
      #pragma unroll
      for (int t = 0; t < 8; ++t) pk.b[t] = cs[(j * 8 + t) * 64 + d];
      int cl = halfTile * 4 + j;  // logical chunk in 64-key tile
      int phys = cl ^ (d & 7);
      *(uint4*)(vTo + ((size_t)batch * 64 + d) * 4096 + tb + phys * 8) = pk.u;
    }
  }
}

// ---------------------------------------------------------------------------
// flash: block = 64 queries (one batch), 4 waves, wave w owns keys
//        [w*1024, w*1024+1024) in 16 tiles of 64; wave-private LDS streams.
// ---------------------------------------------------------------------------
__global__ __launch_bounds__(256, 2) void flash_kernel(
    const bf16* __restrict__ qb, const bf16* __restrict__ kb, const bf16* __restrict__ vT,
    const float* __restrict__ biasArr, float* __restrict__ out)
{
  __shared__ __align__(16) char smem[65536];
  bf16* ksb = (bf16*)smem;            // [4][64*64] K tiles
  bf16* vsb = (bf16*)(smem + 32768);  // [4][64*64] V^T tiles

  const int tid = threadIdx.x;
  const int lane = tid & 63;
  const int wv = tid >> 6;
  const int half = lane >> 5;
  const int ln = lane & 31;

  const int batch = blockIdx.x >> 6;
  const int q0 = (blockIdx.x & 63) << 6;

  // Q fragments for both 32-query blocks (stay in registers)
  bf16x8 qf[2][4];
  const bf16* qbase = qb + ((size_t)batch * 4096 + q0) * 64;
  #pragma unroll
  for (int qk = 0; qk < 2; ++qk)
  #pragma unroll
  for (int s = 0; s < 4; ++s) {
    int qq = (qk << 5) + ln;
    int phys = (2 * s + half) ^ (qq & 7);
    B8 t; t.u = *(const uint4*)(qbase + qq * 64 + phys * 8);
    qf[qk][s] = t.v;
  }

  f32x16 acc[2][2] = {{{}, {}}, {{}, {}}};   // [qblk][d-half], C: col=q, rows=d
  float den0 = 0.f, den1 = 0.f;

  bf16* kds = ksb + wv * 4096;
  bf16* vds = vsb + wv * 4096;
  const bf16* kgb = kb + (size_t)batch * 4096 * 64;
  const bf16* vgb = vT + (size_t)batch * 64 * 4096;
  const float* barr = biasArr + batch * 4096;

  for (int it = 0; it < 16; ++it) {
    const int key0 = wv * 1024 + it * 64;
    __syncthreads();  // drain previous tile's ds_reads before DMA overwrites
    // stage K tile [64 keys][64 d] (8KB contiguous in global)
    const bf16* ksrc = kgb + (size_t)key0 * 64;
    #pragma unroll
    for (int i = 0; i < 8; ++i)
      async16((const char*)ksrc + i * 1024 + lane * 16, (char*)kds + i * 1024);
    // stage V^T tile [64 d][64 keys] (128B per d-row, stride 8KB)
    const bf16* vsrc = vgb + key0;
    #pragma unroll
    for (int i = 0; i < 8; ++i)
      async16((const char*)vsrc + ((size_t)(i * 8 + (lane >> 3)) * 4096 + (lane & 7) * 8) * 2,
              (char*)vds + i * 1024);
    __syncthreads();  // DMA complete

    #pragma unroll
    for (int st = 0; st < 2; ++st) {
      // S^T tile = K * Q^T : rows = 32 keys, cols = 32 queries
      f32x16 s0 = {};
      f32x16 s1 = {};
      #pragma unroll
      for (int s = 0; s < 4; ++s) {
        int key = (st << 5) + ln;
        B8 af; af.u = *(const uint4*)(kds + key * 64 + (((2 * s + half) ^ (key & 7)) << 3));
        s0 = __builtin_amdgcn_mfma_f32_32x32x16_bf16(af.v, qf[0][s], s0, 0, 0, 0);
        s1 = __builtin_amdgcn_mfma_f32_32x32x16_bf16(af.v, qf[1][s], s1, 0, 0, 0);
      }
      // bias per C-row (key): reg r -> key (r&3)+8*(r>>2)+4*half (tile-local)
      float bb[16];
      #pragma unroll
      for (int g = 0; g < 4; ++g)
        *(float4*)&bb[4 * g] = *(const float4*)(barr + key0 + (st << 5) + 8 * g + (half << 2));
      // p = exp2(s*KSC + bias); accumulate denominator; pack bf16 pairs
      uint32_t pk0[8], pk1[8];
      #pragma unroll
      for (int i = 0; i < 8; ++i) {
        float a0 = __builtin_amdgcn_exp2f(fmaf(s0[2 * i],     KSC, bb[2 * i]));
        float a1 = __builtin_amdgcn_exp2f(fmaf(s0[2 * i + 1], KSC, bb[2 * i + 1]));
        float c0 = __builtin_amdgcn_exp2f(fmaf(s1[2 * i],     KSC, bb[2 * i]));
        float c1 = __builtin_amdgcn_exp2f(fmaf(s1[2 * i + 1], KSC, bb[2 * i + 1]));
        den0 += a0 + a1;
        den1 += c0 + c1;
        union { bf16 b[2]; uint32_t u; } u0, u1;
        u0.b[0] = (bf16)a0; u0.b[1] = (bf16)a1;
        u1.b[0] = (bf16)c0; u1.b[1] = (bf16)c1;
        pk0[i] = u0.u; pk1[i] = u1.u;
      }
      // lane-pair exchange: C-layout P^T -> B-operand fragments
      uint32_t xp0[8], xp1[8];
      #pragma unroll
      for (int i = 0; i < 8; ++i) {
        xp0[i] = (uint32_t)__shfl_xor((int)pk0[i], 32);
        xp1[i] = (uint32_t)__shfl_xor((int)pk1[i], 32);
      }
      #pragma unroll
      for (int t = 0; t < 2; ++t) {
        B8 p0f, p1f;
        p0f.w[0] = half ? xp0[4 * t + 2] : pk0[4 * t];
        p0f.w[1] = half ? xp0[4 * t + 3] : pk0[4 * t + 1];
        p0f.w[2] = half ? pk0[4 * t + 2] : xp0[4 * t];
        p0f.w[3] = half ? pk0[4 * t + 3] : xp0[4 * t + 1];
        p1f.w[0] = half ? xp1[4 * t + 2] : pk1[4 * t];
        p1f.w[1] = half ? xp1[4 * t + 3] : pk1[4 * t + 1];
        p1f.w[2] = half ? pk1[4 * t + 2] : xp1[4 * t];
        p1f.w[3] = half ? pk1[4 * t + 3] : xp1[4 * t + 1];
        #pragma unroll
        for (int dh = 0; dh < 2; ++dh) {
          int d = (dh << 5) + ln;
          B8 vf; vf.u = *(const uint4*)(vds + d * 64 +
                          ((((st << 2) + (t << 1) + half) ^ (d & 7)) << 3));
          acc[0][dh] = __builtin_amdgcn_mfma_f32_32x32x16_bf16(vf.v, p0f.v, acc[0][dh], 0, 0, 0);
          acc[1][dh] = __builtin_amdgcn_mfma_f32_32x32x16_bf16(vf.v, p1f.v, acc[1][dh], 0, 0, 0);
        }
      }
    }
  }

  // full denominator per query (each half-lane saw half the keys)
  den0 += __shfl_xor(den0, 32);
  den1 += __shfl_xor(den1, 32);

  // pairwise combine of the 4 key-split partials through LDS (<= 35KB overlay)
  float* nb = (float*)smem;              // [2][64*68]
  float* dn = (float*)(smem + 34816);    // [2][64]

  __syncthreads();
  if (wv >= 2) {
    float* mynb = nb + (wv - 2) * 4352;
    #pragma unroll
    for (int qk = 0; qk < 2; ++qk)
    #pragma unroll
    for (int dh = 0; dh < 2; ++dh)
    #pragma unroll
    for (int g = 0; g < 4; ++g) {
      int q = (qk << 5) + ln;
      int d = 8 * g + (half << 2) + (dh << 5);
      f32x16 a = acc[qk][dh];
      *(float4*)(mynb + q * 68 + d) = make_float4(a[4*g], a[4*g+1], a[4*g+2], a[4*g+3]);
    }
    if (half == 0) {
      dn[(wv - 2) * 64 + ln]      = den0;
      dn[(wv - 2) * 64 + 32 + ln] = den1;
    }
  }
  __syncthreads();
  if (wv < 2) {
    float* pb = nb + wv * 4352;
    #pragma unroll
    for (int qk = 0; qk < 2; ++qk)
    #pragma unroll
    for (int dh = 0; dh < 2; ++dh)
    #pragma unroll
    for (int g = 0; g < 4; ++g) {
      int q = (qk << 5) + ln;
      int d = 8 * g + (half << 2) + (dh << 5);
      float4 t = *(const float4*)(pb + q * 68 + d);
      acc[qk][dh][4*g+0] += t.x; acc[qk][dh][4*g+1] += t.y;
      acc[qk][dh][4*g+2] += t.z; acc[qk][dh][4*g+3] += t.w;
    }
    den0 += dn[wv * 64 + ln];
    den1 += dn[wv * 64 + 32 + ln];
  }
  __syncthreads();
  if (wv < 2) {
    float* mynb = nb + wv * 4352;
    #pragma unroll
    for (int qk = 0; qk < 2; ++qk)
    #pragma unroll
    for (int dh = 0; dh < 2; ++dh)
    #pragma unroll
    for (int g = 0; g < 4; ++g) {
      int q = (qk << 5) + ln;
      int d = 8 * g + (half << 2) + (dh << 5);
      f32x16 a = acc[qk][dh];
      *(float4*)(mynb + q * 68 + d) = make_float4(a[4*g], a[4*g+1], a[4*g+2], a[4*g+3]);
    }
    if (half == 0) {
      dn[wv * 64 + ln]      = den0;
      dn[wv * 64 + 32 + ln] = den1;
    }
  }
  __syncthreads();
  // final: out[q][d] = (nb0+nb1)/(dn0+dn1), coalesced float4 stores
  #pragma unroll
  for (int p = 0; p < 4; ++p) {
    int i = p * 256 + tid;
    int qq = i >> 4;
    int d4 = (i & 15) << 2;
    float4 A = *(const float4*)(nb + qq * 68 + d4);
    float4 Bv = *(const float4*)(nb + 4352 + qq * 68 + d4);
    float dd = dn[qq] + dn[64 + qq];
    float inv = 1.0f / dd;
    float4 o = make_float4((A.x + Bv.x) * inv, (A.y + Bv.y) * inv,
                           (A.z + Bv.z) * inv, (A.w + Bv.w) * inv);
    *(float4*)(out + ((size_t)batch * 4096 + q0 + qq) * 64 + d4) = o;
  }
}

// ---------------------------------------------------------------------------
extern "C" void kernel_launch(void* const* d_in, const int* in_sizes, int n_in,
                              void* d_out, int out_size, void* d_ws, size_t ws_size,
                              hipStream_t stream)
{
  const float* query = (const float*)d_in[0];
  const float* key   = (const float*)d_in[1];
  const float* value = (const float*)d_in[2];
  const int*   mask  = (const int*)d_in[3];
  const float* Wq    = (const float*)d_in[4];
  const float* bq    = (const float*)d_in[5];
  const float* Wk    = (const float*)d_in[6];
  const float* bk    = (const float*)d_in[7];
  const float* Wv    = (const float*)d_in[8];
  const float* bv    = (const float*)d_in[9];
  float* out = (float*)d_out;

  // workspace carve (bf16 elems): q 1M, k 1M, vT 1M, wT 192K, bias 16K floats
  bf16* qb = (bf16*)d_ws;
  bf16* kb = qb + 1048576;
  bf16* vT = kb + 1048576;
  bf16* wT = vT + 1048576;                       // 3*64*1024
  float* biasArr = (float*)((char*)d_ws + 3 * 2097152 + 393216);

  setup_kernel<<<112, 256, 0, stream>>>(Wq, Wk, Wv, mask, wT, biasArr);
  proj_kernel<<<1536, 64, 0, stream>>>(query, key, value, wT, bq, bk, bv, qb, kb, vT);
  flash_kernel<<<256, 256, 0, stream>>>(qb, kb, vT, biasArr, out);
}

// Round 4
// 264.249 us; speedup vs baseline: 1.0739x; 1.0739x over previous
//
#include <hip/hip_runtime.h>
#include <hip/hip_bf16.h>
#include <stdint.h>

// ============================================================================
// Attention: out = softmax(mask((X_q Wq + bq)(X_k Wk + bk)^T / 8)) (X_v Wv + bv)
// B=4 S=4096 H=1024 D=64, fp32 in/out.
//
// Pipeline:
//   setup : W^T -> bf16 (plain [n][1024]), mask -> float bias {0, -1e30}
//   proj  : [R4] 1536 x 1-wave blocks, 32-row strip each. X staged fp32 via
//           global_load_lds (VGPR-free in-flight -> deep pipeline) into a
//           wave-private LDS double buffer; W^T prefetched to registers
//           (L2-hot). No barriers in K-loop; explicit s_waitcnt vmcnt(16)
//           keeps next chunk's 16 loads in flight. R3 (register prefetch)
//           collapsed to ~1.3KB in flight (VGPR-bound) -> 14% HBM, 92 us.
//   flash : S^T = K*Q^T per 32x32 tile, p = exp2(s*0.125*log2e + bias),
//           PV via shfl_xor(32) lane-pair exchange (C-layout -> B-operand),
//           one-pass softmax (logits bounded, no running max needed),
//           4-way key-split per block, pairwise LDS combine.
//
// q/k/vT global tiles keep the chunk-XOR swizzle (c ^ (row&7)) because flash
// stages them into LDS verbatim via global_load_lds and ds_read_b128's them.
// ============================================================================

typedef __bf16 bf16;
typedef __bf16 bf16x8 __attribute__((ext_vector_type(8)));
typedef float f32x16 __attribute__((ext_vector_type(16)));

union B8 { uint4 u; bf16x8 v; uint32_t w[4]; };

#define AS1 __attribute__((address_space(1)))
#define AS3 __attribute__((address_space(3)))

__device__ __forceinline__ void async16(const void* g, void* l) {
  // global -> LDS DMA, 16B per lane; LDS dest = wave-uniform base + lane*16
  __builtin_amdgcn_global_load_lds((AS1 void*)(g), (AS3 void*)(l), 16, 0, 0);
}

#define KSC 0.18033688011112042f  // 0.125 * log2(e)

// ---------------------------------------------------------------------------
// setup: items 0..24575   : W transpose+cast, one 16B wT chunk per thread
//        items 24576..28671: mask -> bias, 4 elements per thread (float4)
// wT layout: [mat][n][1024 k] bf16, plain row-major (read from global by proj)
// ---------------------------------------------------------------------------
__global__ void setup_kernel(const float* __restrict__ Wq, const float* __restrict__ Wk,
                             const float* __restrict__ Wv, const int* __restrict__ mask,
                             bf16* __restrict__ wT, float* __restrict__ biasArr)
{
  int item = blockIdx.x * 256 + threadIdx.x;
  if (item < 24576) {
    int mat = item >> 13;          // 8192 items per matrix
    int rem = item & 8191;
    int n   = rem >> 7;            // 0..63 (col of W)
    int c   = rem & 127;           // 16B chunk id along k
    const float* W = (mat == 0) ? Wq : (mat == 1) ? Wk : Wv;
    union { bf16 b[8]; uint4 u; } pk;
    #pragma unroll
    for (int j = 0; j < 8; ++j)
      pk.b[j] = (bf16)W[(c * 8 + j) * 64 + n];
    bf16* o = wT + mat * 65536;
    *(uint4*)(o + n * 1024 + c * 8) = pk.u;
  } else {
    int i = (item - 24576) << 2;
    const int4 m = *(const int4*)(mask + i);
    float4 b;
    b.x = m.x ? 0.0f : -1e30f;
    b.y = m.y ? 0.0f : -1e30f;
    b.z = m.z ? 0.0f : -1e30f;
    b.w = m.w ? 0.0f : -1e30f;
    *(float4*)(biasArr + i) = b;
  }
}

// ---------------------------------------------------------------------------
// proj: 1536 blocks x 64 threads (1 wave). Strip = 32 rows of one matrix.
// X: global_load_lds fp32 double buffer (8KB chunks), swizzle in src addr.
// W: register prefetch. K-loop barrier-free, manual vmcnt(16).
// ---------------------------------------------------------------------------
__global__ __launch_bounds__(64) void proj_kernel(
    const float* __restrict__ Xq, const float* __restrict__ Xk, const float* __restrict__ Xv,
    const bf16* __restrict__ wT,
    const float* __restrict__ bq, const float* __restrict__ bk, const float* __restrict__ bv,
    bf16* __restrict__ qo, bf16* __restrict__ ko, bf16* __restrict__ vTo)
{
  const int bx = blockIdx.x;
  const int mat = bx >> 9;            // 512 strips per matrix
  const int m0 = (bx & 511) << 5;     // strip base row
  const float* X    = (mat == 0) ? Xq : (mat == 1) ? Xk : Xv;
  const float* bias = (mat == 0) ? bq : (mat == 1) ? bk : bv;
  const bf16* w = wT + mat * 65536;

  __shared__ __align__(16) float xbuf[2][32 * 64];  // 2 x 8 KB X chunk
  __shared__ __align__(16) bf16 cs[32 * 64];        // 4 KB C bounce tile

  const int lane = threadIdx.x;
  const int half = lane >> 5;
  const int ln = lane & 31;

  // DMA lane mapping: instr i covers rows 4i..4i+3; lane -> (row, slot)
  const int drow = lane >> 4;     // row within the 4-row group
  const int dcl  = lane & 15;     // 16B slot within the row (physical)

  const float* xb = X + (size_t)m0 * 1024;
  const bf16*  w0 = w + ln * 1024 + half * 8;
  const bf16*  w1 = w + (ln + 32) * 1024 + half * 8;

  // bias preload; drain so the loop's vmcnt bookkeeping starts at 0
  float b0v = bias[ln];
  float b1v = bias[ln + 32];
  asm volatile("s_waitcnt vmcnt(0)" ::: "memory");

  // stage chunk 0 (8 DMA) + W chunk 0 (8 loads) -> 16 outstanding
  #pragma unroll
  for (int i = 0; i < 8; ++i) {
    int row = i * 4 + drow;
    int sc = (dcl & 8) | ((dcl ^ (row & 7)) & 7);   // logical chunk for slot dcl
    async16(xb + (size_t)row * 1024 + sc * 4, &xbuf[0][i * 256]);
  }
  uint4 wc0[4], wc1[4], wn0[4], wn1[4];
  #pragma unroll
  for (int s = 0; s < 4; ++s) {
    wc0[s] = *(const uint4*)(w0 + s * 16);
    wc1[s] = *(const uint4*)(w1 + s * 16);
  }

  f32x16 acc0 = {};  // n = 0..31
  f32x16 acc1 = {};  // n = 32..63

  for (int c = 0; c < 16; ++c) {
    if (c < 15) {
      const float* src = xb + (c + 1) * 64;
      #pragma unroll
      for (int i = 0; i < 8; ++i) {
        int row = i * 4 + drow;
        int sc = (dcl & 8) | ((dcl ^ (row & 7)) & 7);
        async16(src + (size_t)row * 1024 + sc * 4, &xbuf[(c + 1) & 1][i * 256]);
      }
      #pragma unroll
      for (int s = 0; s < 4; ++s) {
        wn0[s] = *(const uint4*)(w0 + (c + 1) * 64 + s * 16);
        wn1[s] = *(const uint4*)(w1 + (c + 1) * 64 + s * 16);
      }
      // wait chunk c's 16 loads; keep chunk c+1's 16 in flight
      asm volatile("s_waitcnt vmcnt(16)" ::: "memory");
    } else {
      asm volatile("s_waitcnt vmcnt(0)" ::: "memory");
    }
    const float* xl = &xbuf[c & 1][0];
    #pragma unroll
    for (int s = 0; s < 4; ++s) {
      int lc = s * 4 + half * 2;                        // logical 16B chunk
      int p0 = (lc & 8) | ((lc ^ (ln & 7)) & 7);        // physical slots
      int p1 = ((lc + 1) & 8) | (((lc + 1) ^ (ln & 7)) & 7);
      float4 fa = *(const float4*)(xl + ln * 64 + p0 * 4);
      float4 fb = *(const float4*)(xl + ln * 64 + p1 * 4);
      union { bf16 b[8]; bf16x8 v; } af;
      af.b[0] = (bf16)fa.x; af.b[1] = (bf16)fa.y;
      af.b[2] = (bf16)fa.z; af.b[3] = (bf16)fa.w;
      af.b[4] = (bf16)fb.x; af.b[5] = (bf16)fb.y;
      af.b[6] = (bf16)fb.z; af.b[7] = (bf16)fb.w;
      B8 wa; wa.u = wc0[s];
      B8 wb; wb.u = wc1[s];
      acc0 = __builtin_amdgcn_mfma_f32_32x32x16_bf16(af.v, wa.v, acc0, 0, 0, 0);
      acc1 = __builtin_amdgcn_mfma_f32_32x32x16_bf16(af.v, wb.v, acc1, 0, 0, 0);
    }
    #pragma unroll
    for (int s = 0; s < 4; ++s) { wc0[s] = wn0[s]; wc1[s] = wn1[s]; }
  }

  // epilogue: bias add, write un-swizzled [32 m][64 n] bf16 tile to LDS
  #pragma unroll
  for (int r = 0; r < 16; ++r) {
    int mrow = (r & 3) + 8 * (r >> 2) + 4 * half;   // C row map (m74/m101)
    cs[mrow * 64 + ln]      = (bf16)(acc0[r] + b0v);
    cs[mrow * 64 + ln + 32] = (bf16)(acc1[r] + b1v);
  }
  __syncthreads();

  if (mat < 2) {
    // q/k: row-major [16384][64] bf16, chunk c of row s at slot c^(s&7)
    bf16* gout = (mat == 0) ? qo : ko;
    #pragma unroll
    for (int p = 0; p < 4; ++p) {
      int id = p * 64 + lane;
      int r = id >> 3;            // 0..31
      int c = id & 7;
      int phys = c ^ (r & 7);     // m0 % 32 == 0 so (m0+r)&7 == r&7
      *(uint4*)(gout + (size_t)(m0 + r) * 64 + phys * 8) = *(const uint4*)(cs + r * 64 + c * 8);
    }
  } else {
    // v: transposed [b][64 d][4096 s] bf16, chunk swizzle per 64-key tile
    int batch = m0 >> 12;
    int sk = m0 & 4095;           // key offset within batch
    int tb = sk & ~63;            // 64-key tile base
    int halfTile = (sk >> 5) & 1; // which half of the tile this strip covers
    #pragma unroll
    for (int p = 0; p < 4; ++p) {
      int id = p * 64 + lane;
      int d = id >> 2;            // 0..63
      int j = id & 3;             // chunk within strip
      union { bf16 b[8]; uint4 u; } pk;
      #pragma unroll
      for (int t = 0; t < 8; ++t) pk.b[t] = cs[(j * 8 + t) * 64 + d];
      int cl = halfTile * 4 + j;  // logical chunk in 64-key tile
      int phys = cl ^ (d & 7);
      *(uint4*)(vTo + ((size_t)batch * 64 + d) * 4096 + tb + phys * 8) = pk.u;
    }
  }
}

// ---------------------------------------------------------------------------
// flash: block = 64 queries (one batch), 4 waves, wave w owns keys
//        [w*1024, w*1024+1024) in 16 tiles of 64; wave-private LDS streams.
// ---------------------------------------------------------------------------
__global__ __launch_bounds__(256, 2) void flash_kernel(
    const bf16* __restrict__ qb, const bf16* __restrict__ kb, const bf16* __restrict__ vT,
    const float* __restrict__ biasArr, float* __restrict__ out)
{
  __shared__ __align__(16) char smem[65536];
  bf16* ksb = (bf16*)smem;            // [4][64*64] K tiles
  bf16* vsb = (bf16*)(smem + 32768);  // [4][64*64] V^T tiles

  const int tid = threadIdx.x;
  const int lane = tid & 63;
  const int wv = tid >> 6;
  const int half = lane >> 5;
  const int ln = lane & 31;

  const int batch = blockIdx.x >> 6;
  const int q0 = (blockIdx.x & 63) << 6;

  // Q fragments for both 32-query blocks (stay in registers)
  bf16x8 qf[2][4];
  const bf16* qbase = qb + ((size_t)batch * 4096 + q0) * 64;
  #pragma unroll
  for (int qk = 0; qk < 2; ++qk)
  #pragma unroll
  for (int s = 0; s < 4; ++s) {
    int qq = (qk << 5) + ln;
    int phys = (2 * s + half) ^ (qq & 7);
    B8 t; t.u = *(const uint4*)(qbase + qq * 64 + phys * 8);
    qf[qk][s] = t.v;
  }

  f32x16 acc[2][2] = {{{}, {}}, {{}, {}}};   // [qblk][d-half], C: col=q, rows=d
  float den0 = 0.f, den1 = 0.f;

  bf16* kds = ksb + wv * 4096;
  bf16* vds = vsb + wv * 4096;
  const bf16* kgb = kb + (size_t)batch * 4096 * 64;
  const bf16* vgb = vT + (size_t)batch * 64 * 4096;
  const float* barr = biasArr + batch * 4096;

  for (int it = 0; it < 16; ++it) {
    const int key0 = wv * 1024 + it * 64;
    __syncthreads();  // drain previous tile's ds_reads before DMA overwrites
    // stage K tile [64 keys][64 d] (8KB contiguous in global)
    const bf16* ksrc = kgb + (size_t)key0 * 64;
    #pragma unroll
    for (int i = 0; i < 8; ++i)
      async16((const char*)ksrc + i * 1024 + lane * 16, (char*)kds + i * 1024);
    // stage V^T tile [64 d][64 keys] (128B per d-row, stride 8KB)
    const bf16* vsrc = vgb + key0;
    #pragma unroll
    for (int i = 0; i < 8; ++i)
      async16((const char*)vsrc + ((size_t)(i * 8 + (lane >> 3)) * 4096 + (lane & 7) * 8) * 2,
              (char*)vds + i * 1024);
    __syncthreads();  // DMA complete

    #pragma unroll
    for (int st = 0; st < 2; ++st) {
      // S^T tile = K * Q^T : rows = 32 keys, cols = 32 queries
      f32x16 s0 = {};
      f32x16 s1 = {};
      #pragma unroll
      for (int s = 0; s < 4; ++s) {
        int key = (st << 5) + ln;
        B8 af; af.u = *(const uint4*)(kds + key * 64 + (((2 * s + half) ^ (key & 7)) << 3));
        s0 = __builtin_amdgcn_mfma_f32_32x32x16_bf16(af.v, qf[0][s], s0, 0, 0, 0);
        s1 = __builtin_amdgcn_mfma_f32_32x32x16_bf16(af.v, qf[1][s], s1, 0, 0, 0);
      }
      // bias per C-row (key): reg r -> key (r&3)+8*(r>>2)+4*half (tile-local)
      float bb[16];
      #pragma unroll
      for (int g = 0; g < 4; ++g)
        *(float4*)&bb[4 * g] = *(const float4*)(barr + key0 + (st << 5) + 8 * g + (half << 2));
      // p = exp2(s*KSC + bias); accumulate denominator; pack bf16 pairs
      uint32_t pk0[8], pk1[8];
      #pragma unroll
      for (int i = 0; i < 8; ++i) {
        float a0 = __builtin_amdgcn_exp2f(fmaf(s0[2 * i],     KSC, bb[2 * i]));
        float a1 = __builtin_amdgcn_exp2f(fmaf(s0[2 * i + 1], KSC, bb[2 * i + 1]));
        float c0 = __builtin_amdgcn_exp2f(fmaf(s1[2 * i],     KSC, bb[2 * i]));
        float c1 = __builtin_amdgcn_exp2f(fmaf(s1[2 * i + 1], KSC, bb[2 * i + 1]));
        den0 += a0 + a1;
        den1 += c0 + c1;
        union { bf16 b[2]; uint32_t u; } u0, u1;
        u0.b[0] = (bf16)a0; u0.b[1] = (bf16)a1;
        u1.b[0] = (bf16)c0; u1.b[1] = (bf16)c1;
        pk0[i] = u0.u; pk1[i] = u1.u;
      }
      // lane-pair exchange: C-layout P^T -> B-operand fragments
      uint32_t xp0[8], xp1[8];
      #pragma unroll
      for (int i = 0; i < 8; ++i) {
        xp0[i] = (uint32_t)__shfl_xor((int)pk0[i], 32);
        xp1[i] = (uint32_t)__shfl_xor((int)pk1[i], 32);
      }
      #pragma unroll
      for (int t = 0; t < 2; ++t) {
        B8 p0f, p1f;
        p0f.w[0] = half ? xp0[4 * t + 2] : pk0[4 * t];
        p0f.w[1] = half ? xp0[4 * t + 3] : pk0[4 * t + 1];
        p0f.w[2] = half ? pk0[4 * t + 2] : xp0[4 * t];
        p0f.w[3] = half ? pk0[4 * t + 3] : xp0[4 * t + 1];
        p1f.w[0] = half ? xp1[4 * t + 2] : pk1[4 * t];
        p1f.w[1] = half ? xp1[4 * t + 3] : pk1[4 * t + 1];
        p1f.w[2] = half ? pk1[4 * t + 2] : xp1[4 * t];
        p1f.w[3] = half ? pk1[4 * t + 3] : xp1[4 * t + 1];
        #pragma unroll
        for (int dh = 0; dh < 2; ++dh) {
          int d = (dh << 5) + ln;
          B8 vf; vf.u = *(const uint4*)(vds + d * 64 +
                          ((((st << 2) + (t << 1) + half) ^ (d & 7)) << 3));
          acc[0][dh] = __builtin_amdgcn_mfma_f32_32x32x16_bf16(vf.v, p0f.v, acc[0][dh], 0, 0, 0);
          acc[1][dh] = __builtin_amdgcn_mfma_f32_32x32x16_bf16(vf.v, p1f.v, acc[1][dh], 0, 0, 0);
        }
      }
    }
  }

  // full denominator per query (each half-lane saw half the keys)
  den0 += __shfl_xor(den0, 32);
  den1 += __shfl_xor(den1, 32);

  // pairwise combine of the 4 key-split partials through LDS (<= 35KB overlay)
  float* nb = (float*)smem;              // [2][64*68]
  float* dn = (float*)(smem + 34816);    // [2][64]

  __syncthreads();
  if (wv >= 2) {
    float* mynb = nb + (wv - 2) * 4352;
    #pragma unroll
    for (int qk = 0; qk < 2; ++qk)
    #pragma unroll
    for (int dh = 0; dh < 2; ++dh)
    #pragma unroll
    for (int g = 0; g < 4; ++g) {
      int q = (qk << 5) + ln;
      int d = 8 * g + (half << 2) + (dh << 5);
      f32x16 a = acc[qk][dh];
      *(float4*)(mynb + q * 68 + d) = make_float4(a[4*g], a[4*g+1], a[4*g+2], a[4*g+3]);
    }
    if (half == 0) {
      dn[(wv - 2) * 64 + ln]      = den0;
      dn[(wv - 2) * 64 + 32 + ln] = den1;
    }
  }
  __syncthreads();
  if (wv < 2) {
    float* pb = nb + wv * 4352;
    #pragma unroll
    for (int qk = 0; qk < 2; ++qk)
    #pragma unroll
    for (int dh = 0; dh < 2; ++dh)
    #pragma unroll
    for (int g = 0; g < 4; ++g) {
      int q = (qk << 5) + ln;
      int d = 8 * g + (half << 2) + (dh << 5);
      float4 t = *(const float4*)(pb + q * 68 + d);
      acc[qk][dh][4*g+0] += t.x; acc[qk][dh][4*g+1] += t.y;
      acc[qk][dh][4*g+2] += t.z; acc[qk][dh][4*g+3] += t.w;
    }
    den0 += dn[wv * 64 + ln];
    den1 += dn[wv * 64 + 32 + ln];
  }
  __syncthreads();
  if (wv < 2) {
    float* mynb = nb + wv * 4352;
    #pragma unroll
    for (int qk = 0; qk < 2; ++qk)
    #pragma unroll
    for (int dh = 0; dh < 2; ++dh)
    #pragma unroll
    for (int g = 0; g < 4; ++g) {
      int q = (qk << 5) + ln;
      int d = 8 * g + (half << 2) + (dh << 5);
      f32x16 a = acc[qk][dh];
      *(float4*)(mynb + q * 68 + d) = make_float4(a[4*g], a[4*g+1], a[4*g+2], a[4*g+3]);
    }
    if (half == 0) {
      dn[wv * 64 + ln]      = den0;
      dn[wv * 64 + 32 + ln] = den1;
    }
  }
  __syncthreads();
  // final: out[q][d] = (nb0+nb1)/(dn0+dn1), coalesced float4 stores
  #pragma unroll
  for (int p = 0; p < 4; ++p) {
    int i = p * 256 + tid;
    int qq = i >> 4;
    int d4 = (i & 15) << 2;
    float4 A = *(const float4*)(nb + qq * 68 + d4);
    float4 Bv = *(const float4*)(nb + 4352 + qq * 68 + d4);
    float dd = dn[qq] + dn[64 + qq];
    float inv = 1.0f / dd;
    float4 o = make_float4((A.x + Bv.x) * inv, (A.y + Bv.y) * inv,
                           (A.z + Bv.z) * inv, (A.w + Bv.w) * inv);
    *(float4*)(out + ((size_t)batch * 4096 + q0 + qq) * 64 + d4) = o;
  }
}

// ---------------------------------------------------------------------------
extern "C" void kernel_launch(void* const* d_in, const int* in_sizes, int n_in,
                              void* d_out, int out_size, void* d_ws, size_t ws_size,
                              hipStream_t stream)
{
  const float* query = (const float*)d_in[0];
  const float* key   = (const float*)d_in[1];
  const float* value = (const float*)d_in[2];
  const int*   mask  = (const int*)d_in[3];
  const float* Wq    = (const float*)d_in[4];
  const float* bq    = (const float*)d_in[5];
  const float* Wk    = (const float*)d_in[6];
  const float* bk    = (const float*)d_in[7];
  const float* Wv    = (const float*)d_in[8];
  const float* bv    = (const float*)d_in[9];
  float* out = (float*)d_out;

  // workspace carve (bf16 elems): q 1M, k 1M, vT 1M, wT 192K, bias 16K floats
  bf16* qb = (bf16*)d_ws;
  bf16* kb = qb + 1048576;
  bf16* vT = kb + 1048576;
  bf16* wT = vT + 1048576;                       // 3*64*1024
  float* biasArr = (float*)((char*)d_ws + 3 * 2097152 + 393216);

  setup_kernel<<<112, 256, 0, stream>>>(Wq, Wk, Wv, mask, wT, biasArr);
  proj_kernel<<<1536, 64, 0, stream>>>(query, key, value, wT, bq, bk, bv, qb, kb, vT);
  flash_kernel<<<256, 256, 0, stream>>>(qb, kb, vT, biasArr, out);
}